// Round 6
// baseline (260.085 us; speedup 1.0000x reference)
//
#include <hip/hip_runtime.h>
#include <hip/hip_bf16.h>
#include <math.h>

// Problem constants
#define BATCH   8
#define S_LEN   1024
#define D_MODEL 1280
#define DX      768
#define NH      8
#define HD      160
#define LTXT    77
#define NBH     (BATCH*NH)      // 64
#define MKV_PAD 640             // 616 padded to 128-multiple

typedef __attribute__((ext_vector_type(8))) short bf16x8;
typedef __attribute__((ext_vector_type(4))) float f32x4;

// ---------------------------------------------------------------------------
// split_hilo: X fp32 [M,K] -> Y bf16 [M, 2K]  (exact-activation decomposition)
// ---------------------------------------------------------------------------
__global__ __launch_bounds__(256) void split_hilo(
    const float* __restrict__ X, __hip_bfloat16* __restrict__ Y, int M, int K)
{
    const size_t g4 = (size_t)blockIdx.x * 256 + threadIdx.x;
    const size_t total = (size_t)M * K / 4;
    if (g4 >= total) return;
    const size_t g = g4 * 4;
    const int m = (int)(g / K), k = (int)(g % K);
    const float4 x = *(const float4*)&X[g];
    const float xs[4] = {x.x, x.y, x.z, x.w};
    ushort4 hv, lv;
    unsigned short* hp = &hv.x;
    unsigned short* lp = &lv.x;
#pragma unroll
    for (int j = 0; j < 4; ++j) {
        const __hip_bfloat16 hi = __float2bfloat16(xs[j]);
        const __hip_bfloat16 lo = __float2bfloat16(xs[j] - __bfloat162float(hi));
        hp[j] = *(const unsigned short*)&hi;
        lp[j] = *(const unsigned short*)&lo;
    }
    *(ushort4*)&Y[(size_t)m * 2 * K + k]     = hv;
    *(ushort4*)&Y[(size_t)m * 2 * K + K + k] = lv;
}

// ---------------------------------------------------------------------------
// wt_t_dup: W fp32 [K,N] -> BT bf16 [N, 2K], BT[n,k] = BT[n,K+k] = bf16(W[k,n]).
// ---------------------------------------------------------------------------
__global__ __launch_bounds__(256) void wt_t_dup(
    const float* __restrict__ W, __hip_bfloat16* __restrict__ BT, int K, int N)
{
    __shared__ float tile[32][33];
    const int k0 = blockIdx.y * 32, n0 = blockIdx.x * 32;
    const int tx = threadIdx.x & 31, ty = threadIdx.x >> 5;
#pragma unroll
    for (int r = 0; r < 32; r += 8)
        tile[r + ty][tx] = W[(size_t)(k0 + r + ty) * N + n0 + tx];
    __syncthreads();
#pragma unroll
    for (int r = 0; r < 32; r += 8) {
        const int n = n0 + r + ty, k = k0 + tx;
        const __hip_bfloat16 h = __float2bfloat16(tile[tx][r + ty]);
        BT[(size_t)n * 2 * K + k]     = h;
        BT[(size_t)n * 2 * K + K + k] = h;
    }
}

// ---------------------------------------------------------------------------
// wt_t: W fp32 [K,N] -> BT bf16 rows [noff+n][k] (row stride KLD), no dup.
// ---------------------------------------------------------------------------
__global__ __launch_bounds__(256) void wt_t(
    const float* __restrict__ W, __hip_bfloat16* __restrict__ BT,
    int K, int N, int KLD, int noff)
{
    __shared__ float tile[32][33];
    const int k0 = blockIdx.y * 32, n0 = blockIdx.x * 32;
    const int tx = threadIdx.x & 31, ty = threadIdx.x >> 5;
#pragma unroll
    for (int r = 0; r < 32; r += 8)
        tile[r + ty][tx] = W[(size_t)(k0 + r + ty) * N + n0 + tx];
    __syncthreads();
#pragma unroll
    for (int r = 0; r < 32; r += 8) {
        const int n = noff + n0 + r + ty, k = k0 + tx;
        BT[(size_t)n * KLD + k] = __float2bfloat16(tile[tx][r + ty]);
    }
}

// ---------------------------------------------------------------------------
// enc_to_bf16: enc fp32 [616,768] -> encb bf16 [640,768], rows 616..639 zero.
// ---------------------------------------------------------------------------
__global__ __launch_bounds__(256) void enc_to_bf16(
    const float* __restrict__ enc, __hip_bfloat16* __restrict__ encb)
{
    const int g4 = blockIdx.x * 256 + threadIdx.x;
    if (g4 >= MKV_PAD * DX / 4) return;
    const int row = g4 / (DX / 4), c4 = (g4 % (DX / 4)) * 4;
    float4 v = make_float4(0.f, 0.f, 0.f, 0.f);
    if (row < BATCH * LTXT) v = *(const float4*)&enc[(size_t)row * DX + c4];
    const float xs[4] = {v.x, v.y, v.z, v.w};
    ushort4 u;
    unsigned short* up = &u.x;
#pragma unroll
    for (int j = 0; j < 4; ++j) {
        const __hip_bfloat16 h = __float2bfloat16(xs[j]);
        up[j] = *(const unsigned short*)&h;
    }
    *(ushort4*)&encb[(size_t)row * DX + c4] = u;
}

// ---------------------------------------------------------------------------
// MFMA bf16 GEMM, B^T layout: C[M,N] = A[M,KK] @ B[N,KK]^T (+bias)
// 128x128 tile, BK=64, 4 waves. T2 swizzle (pre-swizzled global source +
// XOR'd ds_read), T1 bijective XCD swizzle, and NEW: 2-phase double-buffered
// prefetch (T3-minimum) + T5 setprio around the MFMA cluster.
//   prologue: STAGE(buf0, t=0); barrier(=vmcnt drain)
//   loop:     STAGE(buf^1, t+1)  ||  ds_read+MFMA buf;  barrier;  flip
// One barrier per K-step; staging latency overlaps compute.
// ---------------------------------------------------------------------------
__device__ inline void async_copy16(const void* gptr, void* lptr) {
    __builtin_amdgcn_global_load_lds(
        (const __attribute__((address_space(1))) unsigned*)gptr,
        (__attribute__((address_space(3))) unsigned*)lptr, 16, 0, 0);
}

__global__ __launch_bounds__(256, 2) void gemm_mfma_bt(
    const __hip_bfloat16* __restrict__ A, const __hip_bfloat16* __restrict__ B,
    float* __restrict__ Cf, __hip_bfloat16* __restrict__ Cb,
    float* __restrict__ kout, float* __restrict__ vout,
    int Mreal, int N, int KK, int ntn, const float* __restrict__ bias)
{
    __shared__ __align__(16) __hip_bfloat16 As[2][128 * 64];  // 2 x 16 KB
    __shared__ __align__(16) __hip_bfloat16 Bs[2][128 * 64];  // 2 x 16 KB
    const int t = threadIdx.x;
    const int wave = t >> 6, lane = t & 63;
    const int lr = lane & 15, lg = lane >> 4;
    const int wr = wave >> 1, wc = wave & 1;

    // T1 bijective XCD-chunk swizzle (m204)
    const int nwg = gridDim.x;
    const int q = nwg >> 3, r = nwg & 7;
    const int xcd = blockIdx.x & 7, idx = blockIdx.x >> 3;
    const int swz = (xcd < r ? xcd * (q + 1) : r * (q + 1) + (xcd - r) * q) + idx;
    const int m0 = (swz / ntn) * 128, n0 = (swz % ntn) * 128;

    f32x4 acc[4][4] = {};

    // staging geometry: 16 instrs of 1KB per matrix per K-step; wave does 4+4.
    const int sr = lane >> 3;                   // row within instr
    const int sk = 8 * ((lane & 7) ^ sr);       // T2 pre-swizzled k-elem offset

#define STAGE(buf, k0s)                                                        \
    {                                                                          \
        _Pragma("unroll")                                                      \
        for (int s_ = 0; s_ < 4; ++s_) {                                       \
            const int ti_ = wave * 4 + s_;                                     \
            const int row_ = ti_ * 8 + sr;                                     \
            async_copy16(A + (size_t)(m0 + row_) * KK + (k0s) + sk,            \
                         &As[buf][ti_ * 512]);                                 \
            async_copy16(B + (size_t)(n0 + row_) * KK + (k0s) + sk,            \
                         &Bs[buf][ti_ * 512]);                                 \
        }                                                                      \
    }

#define COMPUTE(buf)                                                           \
    {                                                                          \
        bf16x8 af[4][2], bf_[4][2];                                            \
        _Pragma("unroll")                                                      \
        for (int i = 0; i < 4; ++i)                                            \
            _Pragma("unroll")                                                  \
            for (int ki = 0; ki < 2; ++ki) {                                   \
                const int koff = (ki * 32 + lg * 8) ^ ((lr & 7) * 8);          \
                af[i][ki]  = *(const bf16x8*)(&As[buf][0] +                    \
                                 (wr * 64 + i * 16 + lr) * 64 + koff);         \
                bf_[i][ki] = *(const bf16x8*)(&Bs[buf][0] +                    \
                                 (wc * 64 + i * 16 + lr) * 64 + koff);         \
            }                                                                  \
        __builtin_amdgcn_s_setprio(1);                                         \
        _Pragma("unroll")                                                      \
        for (int ki = 0; ki < 2; ++ki)                                         \
            _Pragma("unroll")                                                  \
            for (int i = 0; i < 4; ++i)                                        \
                _Pragma("unroll")                                              \
                for (int j = 0; j < 4; ++j)                                    \
                    acc[i][j] = __builtin_amdgcn_mfma_f32_16x16x32_bf16(       \
                        af[i][ki], bf_[j][ki], acc[i][j], 0, 0, 0);            \
        __builtin_amdgcn_s_setprio(0);                                         \
    }

    const int nt = KK / 64;       // 40 (big GEMMs) or 12 (KV) -- always even
    STAGE(0, 0)
    __syncthreads();              // drains vmcnt: buf0 ready

    for (int t0 = 0; t0 < nt; t0 += 2) {
        // phase A: prefetch tile t0+1 into buf1, compute buf0
        if (t0 + 1 < nt) STAGE(1, (t0 + 1) * 64)
        COMPUTE(0)
        __syncthreads();          // vmcnt(0) drain: buf1 ready, buf0 free
        // phase B: prefetch tile t0+2 into buf0, compute buf1
        if (t0 + 1 < nt) {
            if (t0 + 2 < nt) STAGE(0, (t0 + 2) * 64)
            COMPUTE(1)
            __syncthreads();      // buf0 ready, buf1 free
        }
    }
#undef STAGE
#undef COMPUTE

    // epilogue: C row = lg*4 + rr, col = lr within fragment (m89 layout)
#pragma unroll
    for (int i = 0; i < 4; ++i) {
#pragma unroll
        for (int j = 0; j < 4; ++j) {
            const int col = n0 + wc * 64 + j * 16 + lr;
            const float bv = bias ? bias[col] : 0.f;
#pragma unroll
            for (int rr = 0; rr < 4; ++rr) {
                const int row = m0 + wr * 64 + i * 16 + lg * 4 + rr;
                const float v = acc[i][j][rr] + bv;
                if (kout) {
                    if (row < Mreal) {
                        if (col < D_MODEL) kout[(size_t)row * D_MODEL + col] = v;
                        else               vout[(size_t)row * D_MODEL + col - D_MODEL] = v;
                    }
                } else if (Cb) {
                    Cb[(size_t)row * N + col] = __float2bfloat16(v);
                } else {
                    Cf[(size_t)row * N + col] = v;
                }
            }
        }
    }
}

// ---------------------------------------------------------------------------
// Ortho-decomp retain transform (unchanged, passing).
// ---------------------------------------------------------------------------
__global__ __launch_bounds__(256) void retain_kernel(
    float* __restrict__ vbuf, const float* __restrict__ tv)
{
    const int l = blockIdx.x % LTXT;
    const int r = blockIdx.x / LTXT;
    const int t = threadIdx.x;

    float g00=0,g01=0,g02=0,g11=0,g12=0,g22=0,tp0=0,tp1=0,tp2=0,pp=0;
    float p_save[10], t0s[10], t1s[10], t2s[10];
#pragma unroll
    for (int it = 0; it < 10; ++it) {
        const int j   = t + it * 256;
        const int m16 = j / HD, d = j % HD;
        const int e = m16 >> 3, h = m16 & 7;
        const float T0 = tv[((size_t)(e*24 +  0 + h) * LTXT + l) * HD + d];
        const float T1 = tv[((size_t)(e*24 +  8 + h) * LTXT + l) * HD + d];
        const float T2 = tv[((size_t)(e*24 + 16 + h) * LTXT + l) * HD + d];
        const float p  = vbuf[((size_t)((e*4 + r) * LTXT + l)) * D_MODEL + h*HD + d];
        p_save[it] = p; t0s[it] = T0; t1s[it] = T1; t2s[it] = T2;
        g00 += T0*T0; g01 += T0*T1; g02 += T0*T2;
        g11 += T1*T1; g12 += T1*T2; g22 += T2*T2;
        tp0 += T0*p;  tp1 += T1*p;  tp2 += T2*p;  pp += p*p;
    }

    __shared__ float part[4][10];
    const int wave = t >> 6, lane = t & 63;
    float vals[10] = {g00,g01,g02,g11,g12,g22,tp0,tp1,tp2,pp};
#pragma unroll
    for (int i = 0; i < 10; ++i) {
        float x = vals[i];
        x += __shfl_down(x, 32); x += __shfl_down(x, 16);
        x += __shfl_down(x,  8); x += __shfl_down(x,  4);
        x += __shfl_down(x,  2); x += __shfl_down(x,  1);
        if (lane == 0) part[wave][i] = x;
    }
    __syncthreads();

    float s[10];
#pragma unroll
    for (int i = 0; i < 10; ++i)
        s[i] = part[0][i] + part[1][i] + part[2][i] + part[3][i];

    const float G[3][3] = {{s[0],s[1],s[2]},{s[1],s[3],s[4]},{s[2],s[4],s[5]}};
    const float tp[3] = {s[6], s[7], s[8]};
    const float ppv = s[9];

    float Pm[3][3];
#pragma unroll
    for (int c = 0; c < 3; ++c)
#pragma unroll
        for (int e = 0; e < 3; ++e) {
            float v = (c == e) ? 1.f : 0.f;
            if (c > e) v -= G[c][e] / G[e][e];
            Pm[c][e] = v;
        }

    const float nP = fmaxf(sqrtf(ppv), 1e-8f);
    float w[3], cosg[3];
#pragma unroll
    for (int c = 0; c < 3; ++c) {
        const float nT = fmaxf(sqrtf(G[c][c]), 1e-8f);
        const float cosv = tp[c] / (nT * nP);
        cosg[c] = 1.f / (1.f + expf(-10.f * (cosv - 0.5f)));
        float d1 = Pm[c][0]*tp[0] + Pm[c][1]*tp[1] + Pm[c][2]*tp[2];
        float d2 = 0.f;
#pragma unroll
        for (int e = 0; e < 3; ++e)
#pragma unroll
            for (int f = 0; f < 3; ++f) d2 += Pm[c][e] * Pm[c][f] * G[e][f];
        float wc = d1 / d2;
        if (isnan(wc)) wc = 0.f;
        if (l == 0)    wc = 0.f;
        w[c] = wc;
    }

    float coef[3];
#pragma unroll
    for (int e = 0; e < 3; ++e)
        coef[e] = cosg[e] * (w[0]*Pm[0][e] + w[1]*Pm[1][e] + w[2]*Pm[2][e]);

#pragma unroll
    for (int it = 0; it < 10; ++it) {
        const int j   = t + it * 256;
        const int m16 = j / HD, d = j % HD;
        const int e = m16 >> 3, h = m16 & 7;
        const float era = coef[0]*t0s[it] + coef[1]*t1s[it] + coef[2]*t2s[it];
        vbuf[((size_t)((e*4 + r) * LTXT + l)) * D_MODEL + h*HD + d] = p_save[it] - era;
    }
}

// ---------------------------------------------------------------------------
// MFMA attention (unchanged, passing).
// ---------------------------------------------------------------------------
#define KSTRIDE 168
#define VSTRIDE 104
#define PSTRIDE 104

__global__ __launch_bounds__(256, 3) void attn_mfma(
    const __hip_bfloat16* __restrict__ qb,
    const float* __restrict__ kbuf,
    const float* __restrict__ vbuf,
    __hip_bfloat16* __restrict__ A2)
{
    __shared__ __hip_bfloat16 KV[160 * VSTRIDE];
    __shared__ __hip_bfloat16 Ps[4][16 * PSTRIDE];
    const int bh = blockIdx.x, b = bh >> 3, h = bh & 7;
    const int qt = blockIdx.y;
    const int t = threadIdx.x, wave = t >> 6, lane = t & 63;
    const int lr = lane & 15, lg = lane >> 4;

    for (int c = t; c < 3200; c += 256) {
        const int l = c / 40, d4 = (c % 40) * 4;
        float4 kv = make_float4(0.f, 0.f, 0.f, 0.f);
        if (l < LTXT) kv = *(const float4*)&kbuf[((size_t)(b * LTXT + l)) * D_MODEL + h * HD + d4];
        const __hip_bfloat16 b0 = __float2bfloat16(kv.x), b1 = __float2bfloat16(kv.y),
                             b2 = __float2bfloat16(kv.z), b3 = __float2bfloat16(kv.w);
        ushort4 u;
        u.x = *(const unsigned short*)&b0; u.y = *(const unsigned short*)&b1;
        u.z = *(const unsigned short*)&b2; u.w = *(const unsigned short*)&b3;
        *(ushort4*)&KV[l * KSTRIDE + d4] = u;
    }
    {
        const __hip_bfloat16 z = __float2bfloat16(0.f);
        for (int i = lane; i < 256; i += 64)
            Ps[wave][(i >> 4) * PSTRIDE + 80 + (i & 15)] = z;
    }
    __syncthreads();

    const int qrow0 = b * S_LEN + qt * 64 + wave * 16;
    const __hip_bfloat16* qp = qb + (size_t)(qrow0 + lr) * D_MODEL + h * HD;
    bf16x8 af[5];
#pragma unroll
    for (int kt = 0; kt < 5; ++kt)
        af[kt] = *(const bf16x8*)&qp[kt * 32 + lg * 8];

    f32x4 accs[5] = {};
#pragma unroll
    for (int j = 0; j < 5; ++j)
#pragma unroll
        for (int kt = 0; kt < 5; ++kt) {
            const bf16x8 bf = *(const bf16x8*)&KV[(j * 16 + lr) * KSTRIDE + kt * 32 + lg * 8];
            accs[j] = __builtin_amdgcn_mfma_f32_16x16x32_bf16(af[kt], bf, accs[j], 0, 0, 0);
        }

    float s[5][4];
    const float scale = 0.07905694150420949f;
#pragma unroll
    for (int j = 0; j < 5; ++j)
#pragma unroll
        for (int r = 0; r < 4; ++r)
            s[j][r] = accs[j][r] * scale;
    if (lr >= 13) { s[4][0] = -1e30f; s[4][1] = -1e30f; s[4][2] = -1e30f; s[4][3] = -1e30f; }

    float rsum[4];
#pragma unroll
    for (int r = 0; r < 4; ++r) {
        float m = s[0][r];
#pragma unroll
        for (int j = 1; j < 5; ++j) m = fmaxf(m, s[j][r]);
        m = fmaxf(m, __shfl_xor(m, 1));
        m = fmaxf(m, __shfl_xor(m, 2));
        m = fmaxf(m, __shfl_xor(m, 4));
        m = fmaxf(m, __shfl_xor(m, 8));
        float sum = 0.f;
#pragma unroll
        for (int j = 0; j < 5; ++j) {
            const float p = __expf(s[j][r] - m);
            s[j][r] = p;
            sum += p;
        }
        sum += __shfl_xor(sum, 1);
        sum += __shfl_xor(sum, 2);
        sum += __shfl_xor(sum, 4);
        sum += __shfl_xor(sum, 8);
        rsum[r] = sum;
    }

#pragma unroll
    for (int j = 0; j < 5; ++j)
#pragma unroll
        for (int r = 0; r < 4; ++r)
            Ps[wave][(lg * 4 + r) * PSTRIDE + j * 16 + lr] = __float2bfloat16(s[j][r]);

    __syncthreads();

    for (int c = t; c < 3840; c += 256) {
        const int l = c / 40, d4 = (c % 40) * 4;
        float4 vv = make_float4(0.f, 0.f, 0.f, 0.f);
        if (l < LTXT) vv = *(const float4*)&vbuf[((size_t)(b * LTXT + l)) * D_MODEL + h * HD + d4];
        KV[(d4 + 0) * VSTRIDE + l] = __float2bfloat16(vv.x);
        KV[(d4 + 1) * VSTRIDE + l] = __float2bfloat16(vv.y);
        KV[(d4 + 2) * VSTRIDE + l] = __float2bfloat16(vv.z);
        KV[(d4 + 3) * VSTRIDE + l] = __float2bfloat16(vv.w);
    }
    __syncthreads();

    bf16x8 pa[3];
#pragma unroll
    for (int kt = 0; kt < 3; ++kt)
        pa[kt] = *(const bf16x8*)&Ps[wave][lr * PSTRIDE + kt * 32 + lg * 8];
    f32x4 acch[10] = {};
#pragma unroll
    for (int dt = 0; dt < 10; ++dt)
#pragma unroll
        for (int kt = 0; kt < 3; ++kt) {
            const bf16x8 vb = *(const bf16x8*)&KV[(dt * 16 + lr) * VSTRIDE + kt * 32 + lg * 8];
            acch[dt] = __builtin_amdgcn_mfma_f32_16x16x32_bf16(pa[kt], vb, acch[dt], 0, 0, 0);
        }

    const float inv[4] = {1.f / rsum[0], 1.f / rsum[1], 1.f / rsum[2], 1.f / rsum[3]};
#pragma unroll
    for (int dt = 0; dt < 10; ++dt) {
        const int col = h * HD + dt * 16 + lr;
#pragma unroll
        for (int r = 0; r < 4; ++r) {
            const int row = qrow0 + lg * 4 + r;
            const float x = acch[dt][r] * inv[r];
            const __hip_bfloat16 hi = __float2bfloat16(x);
            const __hip_bfloat16 lo = __float2bfloat16(x - __bfloat162float(hi));
            A2[(size_t)row * (2 * D_MODEL) + col] = hi;
            A2[(size_t)row * (2 * D_MODEL) + D_MODEL + col] = lo;
        }
    }
}

// ---------------------------------------------------------------------------
extern "C" void kernel_launch(void* const* d_in, const int* in_sizes, int n_in,
                              void* d_out, int out_size, void* d_ws, size_t ws_size,
                              hipStream_t stream)
{
    const float* hidden = (const float*)d_in[0]; // [8,1024,1280]
    const float* enc    = (const float*)d_in[1]; // [8,77,768]
    const float* Wq     = (const float*)d_in[2]; // [1280,1280]
    const float* Wk     = (const float*)d_in[3]; // [768,1280]
    const float* Wv     = (const float*)d_in[4]; // [768,1280]
    const float* Wo     = (const float*)d_in[5]; // [1280,1280]
    const float* bo     = (const float*)d_in[6]; // [1280]
    const float* tv     = (const float*)d_in[7]; // [48,77,160]
    float* out = (float*)d_out;

    const int MQ  = BATCH * S_LEN;  // 8192
    const int MKV = BATCH * LTXT;   // 616
    const int KK  = 2 * D_MODEL;    // 2560

    // ws layout: qreg [8192*1280 f32 region] | kbuf | vbuf | A2 | B2T
    float* qreg = (float*)d_ws;
    float* kbuf = qreg + (size_t)MQ * D_MODEL;
    float* vbuf = kbuf + (size_t)MKV * D_MODEL;
    __hip_bfloat16* A2  = (__hip_bfloat16*)(vbuf + (size_t)MKV * D_MODEL); // [8192,2560]
    __hip_bfloat16* B2T = A2 + (size_t)MQ * KK;                            // [1280,2560]
    __hip_bfloat16* qbf = (__hip_bfloat16*)qreg;                           // [8192,1280] bf16
    __hip_bfloat16* encb = qbf + (size_t)MQ * D_MODEL;                     // [640,768] bf16
    __hip_bfloat16* B2Tkv = B2T;                                           // [2560,768] bf16

    // ---- Q = bf16(hidden @ Wq), exact-activation split MFMA ----
    split_hilo<<<(MQ * D_MODEL / 4 + 255) / 256, 256, 0, stream>>>(hidden, A2, MQ, D_MODEL);
    wt_t_dup<<<dim3(D_MODEL / 32, D_MODEL / 32), 256, 0, stream>>>(Wq, B2T, D_MODEL, D_MODEL);
    gemm_mfma_bt<<<(MQ / 128) * (D_MODEL / 128), 256, 0, stream>>>(
        A2, B2T, nullptr, qbf, nullptr, nullptr, MQ, D_MODEL, KK, D_MODEL / 128, nullptr);

    // ---- fused K|V projection: [640,768]bf16 @ [2560,768]^T -> kbuf,vbuf ----
    enc_to_bf16<<<(MKV_PAD * DX / 4 + 255) / 256, 256, 0, stream>>>(enc, encb);
    wt_t<<<dim3(D_MODEL / 32, DX / 32), 256, 0, stream>>>(Wk, B2Tkv, DX, D_MODEL, DX, 0);
    wt_t<<<dim3(D_MODEL / 32, DX / 32), 256, 0, stream>>>(Wv, B2Tkv, DX, D_MODEL, DX, D_MODEL);
    gemm_mfma_bt<<<(MKV_PAD / 128) * (2 * D_MODEL / 128), 256, 0, stream>>>(
        encb, B2Tkv, nullptr, nullptr, kbuf, vbuf, MKV, 2 * D_MODEL, DX, 2 * D_MODEL / 128, nullptr);

    // ---- concept-erasure retain transform on v (in place, fp32) ----
    retain_kernel<<<4 * LTXT, 256, 0, stream>>>(vbuf, tv);

    // ---- MFMA attention: writes hs as hi/lo split directly into A2 ----
    attn_mfma<<<dim3(NBH, S_LEN / 64), 256, 0, stream>>>(qbf, kbuf, vbuf, A2);

    // ---- out = hs @ Wo + bo ----
    wt_t_dup<<<dim3(D_MODEL / 32, D_MODEL / 32), 256, 0, stream>>>(Wo, B2T, D_MODEL, D_MODEL);
    gemm_mfma_bt<<<(MQ / 128) * (D_MODEL / 128), 256, 0, stream>>>(
        A2, B2T, out, nullptr, nullptr, nullptr, MQ, D_MODEL, KK, D_MODEL / 128, bo);
}

// Round 7
// 173.627 us; speedup vs baseline: 1.4980x; 1.4980x over previous
//
#include <hip/hip_runtime.h>
#include <hip/hip_bf16.h>
#include <math.h>

// Problem constants
#define BATCH   8
#define S_LEN   1024
#define D_MODEL 1280
#define DX      768
#define NH      8
#define HD      160
#define LTXT    77
#define NBH     (BATCH*NH)      // 64
#define MKV_PAD 640             // 616 padded to 128-multiple

typedef _Float16 f16x8 __attribute__((ext_vector_type(8)));
typedef _Float16 f16x4 __attribute__((ext_vector_type(4)));
typedef float    f32x4 __attribute__((ext_vector_type(4)));

// ---------------------------------------------------------------------------
// to_f16: X fp32 [M,K] -> Y f16 [M,K]; rows >= Mreal zeroed (padding).
// ---------------------------------------------------------------------------
__global__ __launch_bounds__(256) void to_f16(
    const float* __restrict__ X, _Float16* __restrict__ Y, int M, int K, int Mreal)
{
    const size_t g4 = (size_t)blockIdx.x * 256 + threadIdx.x;
    const size_t total = (size_t)M * K / 4;
    if (g4 >= total) return;
    const size_t g = g4 * 4;
    const int row = (int)(g / K);
    float4 x = make_float4(0.f, 0.f, 0.f, 0.f);
    if (row < Mreal) x = *(const float4*)&X[g];
    f16x4 o;
    o[0] = (_Float16)x.x; o[1] = (_Float16)x.y;
    o[2] = (_Float16)x.z; o[3] = (_Float16)x.w;
    *(f16x4*)&Y[g] = o;
}

// ---------------------------------------------------------------------------
// wt_t: W fp32 [K,N] -> BT f16 rows [noff+n][k] (row stride KLD).
// ---------------------------------------------------------------------------
__global__ __launch_bounds__(256) void wt_t(
    const float* __restrict__ W, _Float16* __restrict__ BT,
    int K, int N, int KLD, int noff)
{
    __shared__ float tile[32][33];
    const int k0 = blockIdx.y * 32, n0 = blockIdx.x * 32;
    const int tx = threadIdx.x & 31, ty = threadIdx.x >> 5;
#pragma unroll
    for (int r = 0; r < 32; r += 8)
        tile[r + ty][tx] = W[(size_t)(k0 + r + ty) * N + n0 + tx];
    __syncthreads();
#pragma unroll
    for (int r = 0; r < 32; r += 8) {
        const int n = noff + n0 + r + ty, k = k0 + tx;
        BT[(size_t)n * KLD + k] = (_Float16)tile[tx][r + ty];
    }
}

// ---------------------------------------------------------------------------
// MFMA fp16 GEMM, B^T layout: C[M,N] = A[M,KK] @ B[N,KK]^T (+bias)
// Round-4 structure (proven fastest): 128x128 tile, BK=64, 4 waves, single
// 32KB LDS buffer, stage->barrier->compute->barrier. T2 swizzle (pre-swizzled
// global source + XOR'd ds_read), T1 bijective XCD swizzle.
// NOTE: round-5 double-buffer variant REGRESSED (64KB LDS -> occupancy
// 2.5->1.6 blk/CU; implicit inter-block overlap already hides staging: m99).
// Output modes: kout!=0 -> split fp32 into kout/vout; Cb!=0 -> f16; else Cf.
// ---------------------------------------------------------------------------
__device__ inline void async_copy16(const void* gptr, void* lptr) {
    __builtin_amdgcn_global_load_lds(
        (const __attribute__((address_space(1))) unsigned*)gptr,
        (__attribute__((address_space(3))) unsigned*)lptr, 16, 0, 0);
}

__global__ __launch_bounds__(256) void gemm_mfma_bt(
    const _Float16* __restrict__ A, const _Float16* __restrict__ B,
    float* __restrict__ Cf, _Float16* __restrict__ Cb,
    float* __restrict__ kout, float* __restrict__ vout,
    int Mreal, int N, int KK, int ntn, const float* __restrict__ bias)
{
    __shared__ __align__(16) _Float16 As[128 * 64];  // 16 KB
    __shared__ __align__(16) _Float16 Bs[128 * 64];  // 16 KB
    const int t = threadIdx.x;
    const int wave = t >> 6, lane = t & 63;
    const int lr = lane & 15, lg = lane >> 4;
    const int wr = wave >> 1, wc = wave & 1;

    // T1 bijective XCD-chunk swizzle (m204)
    const int nwg = gridDim.x;
    const int q = nwg >> 3, r = nwg & 7;
    const int xcd = blockIdx.x & 7, idx = blockIdx.x >> 3;
    const int swz = (xcd < r ? xcd * (q + 1) : r * (q + 1) + (xcd - r) * q) + idx;
    const int m0 = (swz / ntn) * 128, n0 = (swz % ntn) * 128;

    f32x4 acc[4][4] = {};

    // staging: 16 instrs of 1KB per matrix per K-step; wave does 4+4.
    const int sr = lane >> 3;                   // row within instr
    const int sk = 8 * ((lane & 7) ^ sr);       // T2 pre-swizzled k-elem offset

    for (int k0 = 0; k0 < KK; k0 += 64) {
        __syncthreads();   // previous compute done
#pragma unroll
        for (int s = 0; s < 4; ++s) {
            const int ti = wave * 4 + s;
            const int row = ti * 8 + sr;
            async_copy16(A + (size_t)(m0 + row) * KK + k0 + sk, As + ti * 512);
            async_copy16(B + (size_t)(n0 + row) * KK + k0 + sk, Bs + ti * 512);
        }
        __syncthreads();   // staging complete (barrier drains vmcnt)

        f16x8 af[4][2], bf_[4][2];
#pragma unroll
        for (int i = 0; i < 4; ++i)
#pragma unroll
            for (int ki = 0; ki < 2; ++ki) {
                const int koff = (ki * 32 + lg * 8) ^ ((lr & 7) * 8);
                af[i][ki]  = *(const f16x8*)(As + (wr * 64 + i * 16 + lr) * 64 + koff);
                bf_[i][ki] = *(const f16x8*)(Bs + (wc * 64 + i * 16 + lr) * 64 + koff);
            }
#pragma unroll
        for (int ki = 0; ki < 2; ++ki)
#pragma unroll
            for (int i = 0; i < 4; ++i)
#pragma unroll
                for (int j = 0; j < 4; ++j)
                    acc[i][j] = __builtin_amdgcn_mfma_f32_16x16x32_f16(
                        af[i][ki], bf_[j][ki], acc[i][j], 0, 0, 0);
    }

    // epilogue: C row = lg*4 + rr, col = lr within fragment (m89 layout)
#pragma unroll
    for (int i = 0; i < 4; ++i) {
#pragma unroll
        for (int j = 0; j < 4; ++j) {
            const int col = n0 + wc * 64 + j * 16 + lr;
            const float bv = bias ? bias[col] : 0.f;
#pragma unroll
            for (int rr = 0; rr < 4; ++rr) {
                const int row = m0 + wr * 64 + i * 16 + lg * 4 + rr;
                const float v = acc[i][j][rr] + bv;
                if (kout) {
                    if (row < Mreal) {
                        if (col < D_MODEL) kout[(size_t)row * D_MODEL + col] = v;
                        else               vout[(size_t)row * D_MODEL + col - D_MODEL] = v;
                    }
                } else if (Cb) {
                    Cb[(size_t)row * N + col] = (_Float16)v;
                } else {
                    Cf[(size_t)row * N + col] = v;
                }
            }
        }
    }
}

// ---------------------------------------------------------------------------
// Ortho-decomp retain transform (unchanged, passing).
// ---------------------------------------------------------------------------
__global__ __launch_bounds__(256) void retain_kernel(
    float* __restrict__ vbuf, const float* __restrict__ tv)
{
    const int l = blockIdx.x % LTXT;
    const int r = blockIdx.x / LTXT;
    const int t = threadIdx.x;

    float g00=0,g01=0,g02=0,g11=0,g12=0,g22=0,tp0=0,tp1=0,tp2=0,pp=0;
    float p_save[10], t0s[10], t1s[10], t2s[10];
#pragma unroll
    for (int it = 0; it < 10; ++it) {
        const int j   = t + it * 256;
        const int m16 = j / HD, d = j % HD;
        const int e = m16 >> 3, h = m16 & 7;
        const float T0 = tv[((size_t)(e*24 +  0 + h) * LTXT + l) * HD + d];
        const float T1 = tv[((size_t)(e*24 +  8 + h) * LTXT + l) * HD + d];
        const float T2 = tv[((size_t)(e*24 + 16 + h) * LTXT + l) * HD + d];
        const float p  = vbuf[((size_t)((e*4 + r) * LTXT + l)) * D_MODEL + h*HD + d];
        p_save[it] = p; t0s[it] = T0; t1s[it] = T1; t2s[it] = T2;
        g00 += T0*T0; g01 += T0*T1; g02 += T0*T2;
        g11 += T1*T1; g12 += T1*T2; g22 += T2*T2;
        tp0 += T0*p;  tp1 += T1*p;  tp2 += T2*p;  pp += p*p;
    }

    __shared__ float part[4][10];
    const int wave = t >> 6, lane = t & 63;
    float vals[10] = {g00,g01,g02,g11,g12,g22,tp0,tp1,tp2,pp};
#pragma unroll
    for (int i = 0; i < 10; ++i) {
        float x = vals[i];
        x += __shfl_down(x, 32); x += __shfl_down(x, 16);
        x += __shfl_down(x,  8); x += __shfl_down(x,  4);
        x += __shfl_down(x,  2); x += __shfl_down(x,  1);
        if (lane == 0) part[wave][i] = x;
    }
    __syncthreads();

    float s[10];
#pragma unroll
    for (int i = 0; i < 10; ++i)
        s[i] = part[0][i] + part[1][i] + part[2][i] + part[3][i];

    const float G[3][3] = {{s[0],s[1],s[2]},{s[1],s[3],s[4]},{s[2],s[4],s[5]}};
    const float tp[3] = {s[6], s[7], s[8]};
    const float ppv = s[9];

    float Pm[3][3];
#pragma unroll
    for (int c = 0; c < 3; ++c)
#pragma unroll
        for (int e = 0; e < 3; ++e) {
            float v = (c == e) ? 1.f : 0.f;
            if (c > e) v -= G[c][e] / G[e][e];
            Pm[c][e] = v;
        }

    const float nP = fmaxf(sqrtf(ppv), 1e-8f);
    float w[3], cosg[3];
#pragma unroll
    for (int c = 0; c < 3; ++c) {
        const float nT = fmaxf(sqrtf(G[c][c]), 1e-8f);
        const float cosv = tp[c] / (nT * nP);
        cosg[c] = 1.f / (1.f + expf(-10.f * (cosv - 0.5f)));
        float d1 = Pm[c][0]*tp[0] + Pm[c][1]*tp[1] + Pm[c][2]*tp[2];
        float d2 = 0.f;
#pragma unroll
        for (int e = 0; e < 3; ++e)
#pragma unroll
            for (int f = 0; f < 3; ++f) d2 += Pm[c][e] * Pm[c][f] * G[e][f];
        float wc = d1 / d2;
        if (isnan(wc)) wc = 0.f;
        if (l == 0)    wc = 0.f;
        w[c] = wc;
    }

    float coef[3];
#pragma unroll
    for (int e = 0; e < 3; ++e)
        coef[e] = cosg[e] * (w[0]*Pm[0][e] + w[1]*Pm[1][e] + w[2]*Pm[2][e]);

#pragma unroll
    for (int it = 0; it < 10; ++it) {
        const int j   = t + it * 256;
        const int m16 = j / HD, d = j % HD;
        const int e = m16 >> 3, h = m16 & 7;
        const float era = coef[0]*t0s[it] + coef[1]*t1s[it] + coef[2]*t2s[it];
        vbuf[((size_t)((e*4 + r) * LTXT + l)) * D_MODEL + h*HD + d] = p_save[it] - era;
    }
}

// ---------------------------------------------------------------------------
// MFMA attention, fp16 fragments (same structure as passing round-3 kernel).
// Writes hs as plain fp16 [8192][1280] (out-GEMM A operand).
// ---------------------------------------------------------------------------
#define KSTRIDE 168
#define VSTRIDE 104
#define PSTRIDE 104

__global__ __launch_bounds__(256, 3) void attn_mfma(
    const _Float16* __restrict__ qb,     // [8192][1280] f16
    const float* __restrict__ kbuf,      // [616][1280] fp32
    const float* __restrict__ vbuf,      // [616][1280] fp32 (retained)
    _Float16* __restrict__ hs)           // [8192][1280] f16 out
{
    __shared__ _Float16 KV[160 * VSTRIDE];    // K view: [80][KSTRIDE]
    __shared__ _Float16 Ps[4][16 * PSTRIDE];
    const int bh = blockIdx.x, b = bh >> 3, h = bh & 7;
    const int qt = blockIdx.y;
    const int t = threadIdx.x, wave = t >> 6, lane = t & 63;
    const int lr = lane & 15, lg = lane >> 4;

    // stage K as [80][KSTRIDE] f16, rows >=77 zeroed
    for (int c = t; c < 3200; c += 256) {
        const int l = c / 40, d4 = (c % 40) * 4;
        float4 kv = make_float4(0.f, 0.f, 0.f, 0.f);
        if (l < LTXT) kv = *(const float4*)&kbuf[((size_t)(b * LTXT + l)) * D_MODEL + h * HD + d4];
        f16x4 u;
        u[0] = (_Float16)kv.x; u[1] = (_Float16)kv.y;
        u[2] = (_Float16)kv.z; u[3] = (_Float16)kv.w;
        *(f16x4*)&KV[l * KSTRIDE + d4] = u;
    }
    {
        for (int i = lane; i < 256; i += 64)
            Ps[wave][(i >> 4) * PSTRIDE + 80 + (i & 15)] = (_Float16)0.f;
    }
    __syncthreads();

    const int qrow0 = b * S_LEN + qt * 64 + wave * 16;
    const _Float16* qp = qb + (size_t)(qrow0 + lr) * D_MODEL + h * HD;
    f16x8 af[5];
#pragma unroll
    for (int kt = 0; kt < 5; ++kt)
        af[kt] = *(const f16x8*)&qp[kt * 32 + lg * 8];

    f32x4 accs[5] = {};
#pragma unroll
    for (int j = 0; j < 5; ++j)
#pragma unroll
        for (int kt = 0; kt < 5; ++kt) {
            const f16x8 bf = *(const f16x8*)&KV[(j * 16 + lr) * KSTRIDE + kt * 32 + lg * 8];
            accs[j] = __builtin_amdgcn_mfma_f32_16x16x32_f16(af[kt], bf, accs[j], 0, 0, 0);
        }

    float s[5][4];
    const float scale = 0.07905694150420949f;  // 1/sqrt(160)
#pragma unroll
    for (int j = 0; j < 5; ++j)
#pragma unroll
        for (int r = 0; r < 4; ++r)
            s[j][r] = accs[j][r] * scale;
    if (lr >= 13) { s[4][0] = -1e30f; s[4][1] = -1e30f; s[4][2] = -1e30f; s[4][3] = -1e30f; }

    float rsum[4];
#pragma unroll
    for (int r = 0; r < 4; ++r) {
        float m = s[0][r];
#pragma unroll
        for (int j = 1; j < 5; ++j) m = fmaxf(m, s[j][r]);
        m = fmaxf(m, __shfl_xor(m, 1));
        m = fmaxf(m, __shfl_xor(m, 2));
        m = fmaxf(m, __shfl_xor(m, 4));
        m = fmaxf(m, __shfl_xor(m, 8));
        float sum = 0.f;
#pragma unroll
        for (int j = 0; j < 5; ++j) {
            const float p = __expf(s[j][r] - m);
            s[j][r] = p;
            sum += p;
        }
        sum += __shfl_xor(sum, 1);
        sum += __shfl_xor(sum, 2);
        sum += __shfl_xor(sum, 4);
        sum += __shfl_xor(sum, 8);
        rsum[r] = sum;
    }

#pragma unroll
    for (int j = 0; j < 5; ++j)
#pragma unroll
        for (int r = 0; r < 4; ++r)
            Ps[wave][(lg * 4 + r) * PSTRIDE + j * 16 + lr] = (_Float16)s[j][r];

    __syncthreads();   // all waves done reading K view of KV

    // stage V^T as [160][VSTRIDE] f16, key cols >=77 zeroed (pad to 96)
    for (int c = t; c < 3840; c += 256) {
        const int l = c / 40, d4 = (c % 40) * 4;
        float4 vv = make_float4(0.f, 0.f, 0.f, 0.f);
        if (l < LTXT) vv = *(const float4*)&vbuf[((size_t)(b * LTXT + l)) * D_MODEL + h * HD + d4];
        KV[(d4 + 0) * VSTRIDE + l] = (_Float16)vv.x;
        KV[(d4 + 1) * VSTRIDE + l] = (_Float16)vv.y;
        KV[(d4 + 2) * VSTRIDE + l] = (_Float16)vv.z;
        KV[(d4 + 3) * VSTRIDE + l] = (_Float16)vv.w;
    }
    __syncthreads();

    f16x8 pa[3];
#pragma unroll
    for (int kt = 0; kt < 3; ++kt)
        pa[kt] = *(const f16x8*)&Ps[wave][lr * PSTRIDE + kt * 32 + lg * 8];
    f32x4 acch[10] = {};
#pragma unroll
    for (int dt = 0; dt < 10; ++dt)
#pragma unroll
        for (int kt = 0; kt < 3; ++kt) {
            const f16x8 vb = *(const f16x8*)&KV[(dt * 16 + lr) * VSTRIDE + kt * 32 + lg * 8];
            acch[dt] = __builtin_amdgcn_mfma_f32_16x16x32_f16(pa[kt], vb, acch[dt], 0, 0, 0);
        }

    const float inv[4] = {1.f / rsum[0], 1.f / rsum[1], 1.f / rsum[2], 1.f / rsum[3]};
#pragma unroll
    for (int dt = 0; dt < 10; ++dt) {
        const int col = h * HD + dt * 16 + lr;
#pragma unroll
        for (int r = 0; r < 4; ++r) {
            const int row = qrow0 + lg * 4 + r;
            hs[(size_t)row * D_MODEL + col] = (_Float16)(acch[dt][r] * inv[r]);
        }
    }
}

// ---------------------------------------------------------------------------
extern "C" void kernel_launch(void* const* d_in, const int* in_sizes, int n_in,
                              void* d_out, int out_size, void* d_ws, size_t ws_size,
                              hipStream_t stream)
{
    const float* hidden = (const float*)d_in[0]; // [8,1024,1280]
    const float* enc    = (const float*)d_in[1]; // [8,77,768]
    const float* Wq     = (const float*)d_in[2]; // [1280,1280]
    const float* Wk     = (const float*)d_in[3]; // [768,1280]
    const float* Wv     = (const float*)d_in[4]; // [768,1280]
    const float* Wo     = (const float*)d_in[5]; // [1280,1280]
    const float* bo     = (const float*)d_in[6]; // [1280]
    const float* tv     = (const float*)d_in[7]; // [48,77,160]
    float* out = (float*)d_out;

    const int MQ  = BATCH * S_LEN;  // 8192
    const int MKV = BATCH * LTXT;   // 616

    // ws layout (all fp16 GEMM operands, no hi/lo split):
    float*    kbuf  = (float*)d_ws;                          // [616,1280] f32
    float*    vbuf  = kbuf + (size_t)MKV * D_MODEL;          // [616,1280] f32
    _Float16* qf    = (_Float16*)(vbuf + (size_t)MKV * D_MODEL); // [8192,1280]
    _Float16* hsf   = qf  + (size_t)MQ * D_MODEL;            // [8192,1280]
    _Float16* hidf  = hsf + (size_t)MQ * D_MODEL;            // [8192,1280]
    _Float16* encb  = hidf + (size_t)MQ * D_MODEL;           // [640,768]
    _Float16* B2T   = encb + (size_t)MKV_PAD * DX;           // [1280,1280]
    _Float16* B2Tkv = B2T  + (size_t)D_MODEL * D_MODEL;      // [2560,768]

    // ---- Q = f16(hidden @ Wq) ----
    to_f16<<<(MQ * D_MODEL / 4 + 255) / 256, 256, 0, stream>>>(hidden, hidf, MQ, D_MODEL, MQ);
    wt_t<<<dim3(D_MODEL / 32, D_MODEL / 32), 256, 0, stream>>>(Wq, B2T, D_MODEL, D_MODEL, D_MODEL, 0);
    gemm_mfma_bt<<<(MQ / 128) * (D_MODEL / 128), 256, 0, stream>>>(
        hidf, B2T, nullptr, qf, nullptr, nullptr, MQ, D_MODEL, D_MODEL, D_MODEL / 128, nullptr);

    // ---- fused K|V projection: [640,768]f16 @ [2560,768]^T -> kbuf,vbuf f32 ----
    to_f16<<<(MKV_PAD * DX / 4 + 255) / 256, 256, 0, stream>>>(enc, encb, MKV_PAD, DX, MKV);
    wt_t<<<dim3(D_MODEL / 32, DX / 32), 256, 0, stream>>>(Wk, B2Tkv, DX, D_MODEL, DX, 0);
    wt_t<<<dim3(D_MODEL / 32, DX / 32), 256, 0, stream>>>(Wv, B2Tkv, DX, D_MODEL, DX, D_MODEL);
    gemm_mfma_bt<<<(MKV_PAD / 128) * (2 * D_MODEL / 128), 256, 0, stream>>>(
        encb, B2Tkv, nullptr, nullptr, kbuf, vbuf, MKV, 2 * D_MODEL, DX, 2 * D_MODEL / 128, nullptr);

    // ---- concept-erasure retain transform on v (in place, fp32) ----
    retain_kernel<<<4 * LTXT, 256, 0, stream>>>(vbuf, tv);

    // ---- MFMA attention (fp16): writes hs f16 ----
    attn_mfma<<<dim3(NBH, S_LEN / 64), 256, 0, stream>>>(qf, kbuf, vbuf, hsf);

    // ---- out = hs @ Wo + bo ----
    wt_t<<<dim3(D_MODEL / 32, D_MODEL / 32), 256, 0, stream>>>(Wo, B2T, D_MODEL, D_MODEL, D_MODEL, 0);
    gemm_mfma_bt<<<(MQ / 128) * (D_MODEL / 128), 256, 0, stream>>>(
        hsf, B2T, out, nullptr, nullptr, nullptr, MQ, D_MODEL, D_MODEL, D_MODEL / 128, bo);
}